// Round 7
// baseline (621.866 us; speedup 1.0000x reference)
//
#include <hip/hip_runtime.h>
#include <hip/hip_bf16.h>
#include <float.h>

#define NB 32
#define NBCE 32
#define L 128
#define NT 1024
#define R 132                      /* row stride of mirror-square */
#define PAD 256                    /* tail pad: leveled overreads stay in-array */
#define LOGMIN -87.49823f          /* ln(1e-38) */

// ---- mask dtype runtime detection (element [0] is guaranteed true: lens >= 64) ----
__device__ __forceinline__ int mask_mode(const void* p) {
    unsigned int v = ((const unsigned int*)p)[0];
    if (v == 1u) return 1;
    if (v == 0x3F800000u) return 2;
    return 0;
}
__device__ __forceinline__ bool mask_at(const void* p, int mode, int idx) {
    if (mode == 1) return ((const int*)p)[idx] != 0;
    if (mode == 2) return ((const float*)p)[idx] != 0.0f;
    return ((const unsigned char*)p)[idx] != 0;
}

__device__ __forceinline__ float lse2(float a, float b) {
    return fmaxf(a, b) + log1pf(__expf(-fabsf(a - b)));
}

// ---- DPP butterflies over aligned subgroups of 8 or 16 lanes (R4-proven) ----
template<int C>
__device__ __forceinline__ float dppf(float x) {
    return __int_as_float(__builtin_amdgcn_mov_dpp(__float_as_int(x), C, 0xF, 0xF, true));
}
template<int T>
__device__ __forceinline__ float bfly_max(float x) {
    x = fmaxf(x, dppf<0xB1>(x));
    x = fmaxf(x, dppf<0x4E>(x));
    x = fmaxf(x, dppf<0x141>(x));
    if (T == 16) x = fmaxf(x, dppf<0x140>(x));
    return x;
}
template<int T>
__device__ __forceinline__ float bfly_add(float x) {
    x += dppf<0xB1>(x);
    x += dppf<0x4E>(x);
    x += dppf<0x141>(x);
    if (T == 16) x += dppf<0x140>(x);
    return x;
}

// ---- batched loads: ALL 2K ds_reads independent, no reduction between them ----
template<int T, int K>
__device__ __forceinline__ void load_batch(float* v, int sub, int nterm,
                                           const float* p1, const float* p2) {
    p1 += sub; p2 += sub;
    float x[K], y[K];
#pragma unroll
    for (int k = 0; k < K; ++k) { x[k] = p1[k * T]; y[k] = p2[k * T]; }
#pragma unroll
    for (int k = 0; k < K; ++k)
        v[k] = (sub + k * T < nterm) ? (x[k] + y[k]) : -FLT_MAX;
}

// leveled load + local max. nmax must be a wave-uniform upper bound on nterm.
// Returns slot count KL actually loaded (0 if nmax <= 0).
template<int T, int KMAX>
__device__ __forceinline__ int lse_load(float* v, int sub, int nterm, int nmax,
                                        const float* p1, const float* p2, float& mloc) {
    int KL = 0;
    if (nmax > 0) {
        if (KMAX >= 16 && nmax > 8 * T)      { load_batch<T, (KMAX >= 16 ? 16 : 2)>(v, sub, nterm, p1, p2); KL = 16; }
        else if (KMAX >= 8 && nmax > 4 * T)  { load_batch<T, (KMAX >= 8  ?  8 : 2)>(v, sub, nterm, p1, p2); KL = 8; }
        else if (KMAX >= 4 && nmax > 2 * T)  { load_batch<T, (KMAX >= 4  ?  4 : 2)>(v, sub, nterm, p1, p2); KL = 4; }
        else                                 { load_batch<T, 2>(v, sub, nterm, p1, p2); KL = 2; }
#pragma unroll
        for (int k = 0; k < KMAX; ++k) { if (k >= KL) break; mloc = fmaxf(mloc, v[k]); }
    }
    return KL;
}
template<int KMAX>
__device__ __forceinline__ void exp_sum(const float* v, int KL, float M, float& s) {
#pragma unroll
    for (int k = 0; k < KMAX; ++k) { if (k >= KL) break; s += __expf(v[k] - M); }
}

// ================= fused kernel: blocks [0,NB) = per-batch DP; [NB,NB+NBCE) = BCE =================
__global__ __launch_bounds__(NT, 1) void tree_dp_kernel(
    const float* __restrict__ logits,
    const int*   __restrict__ spans_ind,
    const void*  __restrict__ maskspan,
    const float* __restrict__ ph, const float* __restrict__ pt,
    const int* __restrict__ ph_ind, const int* __restrict__ pt_ind,
    const void* __restrict__ maskarc,
    double*      __restrict__ ws)
{
    const int tid = threadIdx.x;

    // ---------------- BCE blocks ----------------
    if (blockIdx.x >= NB) {
        const int mode = mask_mode(maskarc);
        const int tot = NB * L * L;
        double sph = 0.0, spt = 0.0, cnt = 0.0;
        for (int idx = (blockIdx.x - NB) * NT + tid; idx < tot; idx += NBCE * NT) {
            if (mask_at(maskarc, mode, idx)) {
                float x = ph[idx]; float y = (float)ph_ind[idx];
                sph += (double)(fmaxf(x, 0.0f) - x * y + log1pf(__expf(-fabsf(x))));
                x = pt[idx]; y = (float)pt_ind[idx];
                spt += (double)(fmaxf(x, 0.0f) - x * y + log1pf(__expf(-fabsf(x))));
                cnt += 1.0;
            }
        }
        for (int off = 32; off > 0; off >>= 1) {
            sph += __shfl_down(sph, off);
            spt += __shfl_down(spt, off);
            cnt += __shfl_down(cnt, off);
        }
        if ((tid & 63) == 0) {
            atomicAdd(&ws[2], sph); atomicAdd(&ws[3], spt); atomicAdd(&ws[4], cnt);
        }
        return;
    }

    // ---------------- DP blocks ----------------
    __shared__ float Am[L * R + PAD];   // mirror-square alpha (slots init to sc)
    __shared__ float Gm[L * R + PAD];   // mirror-square gamma (slots init to sc)

    const int b = blockIdx.x;
    const int mbase = b * L * L;
    const int mode = mask_mode(maskspan);

    int pred = (tid < L) && mask_at(maskspan, mode, mbase + tid);
    const int n = __syncthreads_count(pred);

    const float* lg = logits + (size_t)b * L * L * 2;

    // ---- init: sc into both mirror halves ----
    for (int e = tid; e < L * L; e += NT) {
        int i = e >> 7, j = e & (L - 1);
        if (i <= j && j < n) {
            const float* p = lg + (size_t)e * 2;
            float v = lse2(p[0], p[1]);
            Am[i * R + j] = v; Am[j * R + i] = v;
            Gm[i * R + j] = v; Gm[j * R + i] = v;
        }
    }
    __syncthreads();

    // ---- inside: widths 1..n-1 (R4 structure, batched loads) ----
    // alpha[i,j] = sc + LSE_t( A[i,i+t] + A[i+1+t,j] ), t in [0,w)
    for (int w = 1; w < n; ++w) {
        int c = n - w;
        if (c > 64) {                       // T=8, w <= 63 -> KMAX 8
            int cell = tid >> 3, sub = tid & 7;
            if (cell < c) {
                int i = cell, j = i + w;
                float v[8]; float mloc = -FLT_MAX;
                int KL = lse_load<8, 8>(v, sub, w, w, &Am[i * R + i], &Am[j * R + i + 1], mloc);
                float M = bfly_max<8>(mloc);
                float s = 0.0f; exp_sum<8>(v, KL, M, s);
                float S = bfly_add<8>(s);
                if (sub == 0) {
                    float val = Am[i * R + j] + M + __logf(S);   // slot holds sc
                    Am[i * R + j] = val; Am[j * R + i] = val;
                }
            }
        } else {                            // T=16, w <= 127 -> KMAX 8
            int cell = tid >> 4, sub = tid & 15;
            if (cell < c) {
                int i = cell, j = i + w;
                float v[8]; float mloc = -FLT_MAX;
                int KL = lse_load<16, 8>(v, sub, w, w, &Am[i * R + i], &Am[j * R + i + 1], mloc);
                float M = bfly_max<16>(mloc);
                float s = 0.0f; exp_sum<8>(v, KL, M, s);
                float S = bfly_add<16>(s);
                if (sub == 0) {
                    float val = Am[i * R + j] + M + __logf(S);
                    Am[i * R + j] = val; Am[j * R + i] = val;
                }
            }
        }
        __syncthreads();
    }

    const float logZ = Am[n - 1];   // alpha[0, n-1]

    // ---- outside: widths n-2..1 (R4 structure, batched loads) ----
    // gamma[i,j] = sc + LSE( k>j: G[i,k]+A[j+1,k] ; k<i: G[k,j]+A[k,i-1] )
    for (int w = n - 2; w >= 1; --w) {
        int c = n - w;
        if (c > 64) {                       // T=8, streams <= 126 -> KMAX 16
            int cell = tid >> 3, sub = tid & 7;
            int i0 = (tid >> 6) << 3;       // wave's first cell (uniform)
            if (cell < c) {
                int i = cell, j = i + w;
                int nt1 = n - 1 - j;
                int im1 = (i >= 1) ? i - 1 : 0;
                int nAmax = n - 1 - i0 - w;          // uniform bound for stream 1
                int nBmax = i0 + 7;                  // uniform bound for stream 2
                float v1[16], v2[16]; float mloc = -FLT_MAX;
                int K1 = lse_load<8, 16>(v1, sub, nt1, nAmax,
                                         &Gm[i * R + j + 1], &Am[(j + 1) * R + j + 1], mloc);
                int K2 = lse_load<8, 16>(v2, sub, i, nBmax,
                                         &Gm[j * R], &Am[im1 * R], mloc);
                float M = bfly_max<8>(mloc);
                float s = 0.0f;
                exp_sum<16>(v1, K1, M, s);
                exp_sum<16>(v2, K2, M, s);
                float S = bfly_add<8>(s);
                if (sub == 0) {
                    float val = Gm[i * R + j] + M + __logf(S);   // slot holds sc
                    Gm[i * R + j] = val; Gm[j * R + i] = val;
                }
            }
        } else {                            // T=16, streams <= 63 -> KMAX 4
            int cell = tid >> 4, sub = tid & 15;
            int i0 = (tid >> 6) << 2;
            if (cell < c) {
                int i = cell, j = i + w;
                int nt1 = n - 1 - j;
                int im1 = (i >= 1) ? i - 1 : 0;
                int nAmax = n - 1 - i0 - w;
                int nBmax = i0 + 3;
                float v1[4], v2[4]; float mloc = -FLT_MAX;
                int K1 = lse_load<16, 4>(v1, sub, nt1, nAmax,
                                         &Gm[i * R + j + 1], &Am[(j + 1) * R + j + 1], mloc);
                int K2 = lse_load<16, 4>(v2, sub, i, nBmax,
                                         &Gm[j * R], &Am[im1 * R], mloc);
                float M = bfly_max<16>(mloc);
                float s = 0.0f;
                exp_sum<4>(v1, K1, M, s);
                exp_sum<4>(v2, K2, M, s);
                float S = bfly_add<16>(s);
                if (sub == 0) {
                    float val = Gm[i * R + j] + M + __logf(S);
                    Gm[i * R + j] = val; Gm[j * R + i] = val;
                }
            }
        }
        __syncthreads();
    }

    // ============ loss phase ============
    const int* si = spans_ind + mbase;
    double local = 0.0;
    {
        int cell = tid >> 3, sub = tid & 7;       // T=8, streams <= 127 -> KMAX 16
        int i0 = (tid >> 6) << 3;
        if (cell < n) {
            int i = cell;
            int nt1 = n - 1 - i;
            int im1 = (i >= 1) ? i - 1 : 0;
            int nAmax = n - 1 - i0;
            int nBmax = i0 + 7;
            float v1[16], v2[16]; float mloc = -FLT_MAX;
            int K1 = lse_load<8, 16>(v1, sub, nt1, nAmax,
                                     &Gm[i * R + i + 1], &Am[(i + 1) * R + i + 1], mloc);
            int K2 = lse_load<8, 16>(v2, sub, i, nBmax,
                                     &Gm[i * R], &Am[im1 * R], mloc);
            float M = bfly_max<8>(mloc);
            float s = 0.0f;
            exp_sum<16>(v1, K1, M, s);
            exp_sum<16>(v2, K2, M, s);
            float S = bfly_add<8>(s);
            if (sub == 0) {
                float beta_ii = M + __logf(S);
                const float* p = lg + ((size_t)i * L + i) * 2;
                int ind = si[i * L + i];
                float lc = (ind == 2) ? p[1] : p[0];
                float logm = beta_ii - logZ + lc;     // alpha_ii == sc_ii cancels
                local += (double)fmaxf(logm, LOGMIN);
            }
        }
    }
    for (int e = tid; e < L * L; e += NT) {
        int i = e >> 7, j = e & (L - 1);
        if (i < j && j < n) {
            const float* p = lg + (size_t)e * 2;
            float a = p[0], cc = p[1];
            float sc = lse2(a, cc);
            int ind = si[e];
            float lc = (ind == 2) ? cc : a;
            float logm = Am[i * R + j] + Gm[i * R + j] - logZ + lc - 2.0f * sc;
            local += (double)fmaxf(logm, LOGMIN);
        }
    }
    for (int off = 32; off > 0; off >>= 1)
        local += __shfl_down(local, off);
    if ((tid & 63) == 0) atomicAdd(&ws[0], local);
    if (tid == 0) atomicAdd(&ws[1], (double)n);
}

// ================= finalize =================
__global__ void finalize_kernel(const double* __restrict__ ws, float* __restrict__ out) {
    double loss_spans = -ws[0] / ws[1];
    double bce = (ws[2] + ws[3]) / ws[4];
    out[0] = (float)(0.5 * loss_spans + 0.5 * bce);
}

extern "C" void kernel_launch(void* const* d_in, const int* in_sizes, int n_in,
                              void* d_out, int out_size, void* d_ws, size_t ws_size,
                              hipStream_t stream) {
    (void)in_sizes; (void)n_in; (void)out_size; (void)ws_size;
    const float* span_logits = (const float*)d_in[0];
    const float* ph          = (const float*)d_in[1];
    const float* pt          = (const float*)d_in[2];
    /* d_in[3] = ph_arc: unused by reference */
    const int*   spans_ind   = (const int*)d_in[4];
    const int*   ph_ind      = (const int*)d_in[5];
    const int*   pt_ind      = (const int*)d_in[6];
    const void*  maskspan    = d_in[7];
    const void*  maskarc     = d_in[8];
    double* ws = (double*)d_ws;
    float* out = (float*)d_out;

    hipMemsetAsync(d_ws, 0, 5 * sizeof(double), stream);
    hipLaunchKernelGGL(tree_dp_kernel, dim3(NB + NBCE), dim3(NT), 0, stream,
                       span_logits, spans_ind, maskspan,
                       ph, pt, ph_ind, pt_ind, maskarc, ws);
    hipLaunchKernelGGL(finalize_kernel, dim3(1), dim3(1), 0, stream, ws, out);
}

// Round 8
// 508.934 us; speedup vs baseline: 1.2219x; 1.2219x over previous
//
#include <hip/hip_runtime.h>
#include <hip/hip_bf16.h>
#include <float.h>

#define NB 32
#define NBCE 32
#define L 128
#define NT 1024
#define R 132                      /* row stride of mirror-square */
#define PAD 256                    /* tail pad: leveled overreads stay in-array */
#define LOGMIN -87.49823f          /* ln(1e-38) */

// ---- mask dtype runtime detection (element [0] is guaranteed true: lens >= 64) ----
__device__ __forceinline__ int mask_mode(const void* p) {
    unsigned int v = ((const unsigned int*)p)[0];
    if (v == 1u) return 1;
    if (v == 0x3F800000u) return 2;
    return 0;
}
__device__ __forceinline__ bool mask_at(const void* p, int mode, int idx) {
    if (mode == 1) return ((const int*)p)[idx] != 0;
    if (mode == 2) return ((const float*)p)[idx] != 0.0f;
    return ((const unsigned char*)p)[idx] != 0;
}

__device__ __forceinline__ float lse2(float a, float b) {
    return fmaxf(a, b) + log1pf(__expf(-fabsf(a - b)));
}

// ---- DPP butterflies over aligned subgroups of 8 or 16 lanes (R4-proven) ----
template<int C>
__device__ __forceinline__ float dppf(float x) {
    return __int_as_float(__builtin_amdgcn_mov_dpp(__float_as_int(x), C, 0xF, 0xF, true));
}
template<int T>
__device__ __forceinline__ float bfly_max(float x) {
    x = fmaxf(x, dppf<0xB1>(x));
    x = fmaxf(x, dppf<0x4E>(x));
    x = fmaxf(x, dppf<0x141>(x));
    if (T == 16) x = fmaxf(x, dppf<0x140>(x));
    return x;
}
template<int T>
__device__ __forceinline__ float bfly_add(float x) {
    x += dppf<0xB1>(x);
    x += dppf<0x4E>(x);
    x += dppf<0x141>(x);
    if (T == 16) x += dppf<0x140>(x);
    return x;
}

// ---- chunked batch load: K <= 8 slot-pairs, all 2K ds_reads issued before any use.
// a[]/b[] are chunk-local (<=16 temp regs, reused across chunks) -> no spill.
template<int T, int K>
__device__ __forceinline__ void loadK8(float* v, int sub, int nterm, int slot0,
                                       const float* __restrict__ p1,
                                       const float* __restrict__ p2, float& mloc) {
    float a[K], b[K];
#pragma unroll
    for (int k = 0; k < K; ++k) a[k] = p1[sub + (slot0 + k) * T];
#pragma unroll
    for (int k = 0; k < K; ++k) b[k] = p2[sub + (slot0 + k) * T];
#pragma unroll
    for (int k = 0; k < K; ++k) {
        float val = (sub + (slot0 + k) * T < nterm) ? (a[k] + b[k]) : -FLT_MAX;
        v[slot0 + k] = val; mloc = fmaxf(mloc, val);
    }
}

// leveled dispatch; nmax must be wave-uniform (scalar branch). Returns slots loaded.
template<int T, int KMAX>
__device__ __forceinline__ int load_disp(float* v, int sub, int nterm, int nmax,
                                         const float* p1, const float* p2, float& mloc) {
    if (nmax <= 0) return 0;
    const int need = (nmax + T - 1) / T;
    if constexpr (KMAX >= 16) {
        if (need > 8) {
            loadK8<T, 8>(v, sub, nterm, 0, p1, p2, mloc);
            loadK8<T, 8>(v, sub, nterm, 8, p1, p2, mloc);
            return 16;
        }
    }
    if constexpr (KMAX >= 8) {
        if (need > 4) { loadK8<T, 8>(v, sub, nterm, 0, p1, p2, mloc); return 8; }
    }
    if (need > 2) { loadK8<T, 4>(v, sub, nterm, 0, p1, p2, mloc); return 4; }
    loadK8<T, 2>(v, sub, nterm, 0, p1, p2, mloc);
    return 2;
}
template<int KMAX>
__device__ __forceinline__ void exp_sum(const float* v, int KL, float M, float& s) {
#pragma unroll
    for (int k = 0; k < KMAX; ++k) { if (k >= KL) break; s += __expf(v[k] - M); }
}

// ================= fused kernel: blocks [0,NB) = per-batch DP; [NB,NB+NBCE) = BCE =================
__global__ __launch_bounds__(NT, 1) void tree_dp_kernel(
    const float* __restrict__ logits,
    const int*   __restrict__ spans_ind,
    const void*  __restrict__ maskspan,
    const float* __restrict__ ph, const float* __restrict__ pt,
    const int* __restrict__ ph_ind, const int* __restrict__ pt_ind,
    const void* __restrict__ maskarc,
    double*      __restrict__ ws)
{
    const int tid = threadIdx.x;

    // ---------------- BCE blocks ----------------
    if (blockIdx.x >= NB) {
        const int mode = mask_mode(maskarc);
        const int tot = NB * L * L;
        double sph = 0.0, spt = 0.0, cnt = 0.0;
        for (int idx = (blockIdx.x - NB) * NT + tid; idx < tot; idx += NBCE * NT) {
            if (mask_at(maskarc, mode, idx)) {
                float x = ph[idx]; float y = (float)ph_ind[idx];
                sph += (double)(fmaxf(x, 0.0f) - x * y + log1pf(__expf(-fabsf(x))));
                x = pt[idx]; y = (float)pt_ind[idx];
                spt += (double)(fmaxf(x, 0.0f) - x * y + log1pf(__expf(-fabsf(x))));
                cnt += 1.0;
            }
        }
        for (int off = 32; off > 0; off >>= 1) {
            sph += __shfl_down(sph, off);
            spt += __shfl_down(spt, off);
            cnt += __shfl_down(cnt, off);
        }
        if ((tid & 63) == 0) {
            atomicAdd(&ws[2], sph); atomicAdd(&ws[3], spt); atomicAdd(&ws[4], cnt);
        }
        return;
    }

    // ---------------- DP blocks ----------------
    __shared__ float Am[L * R + PAD];   // mirror-square alpha (slots init to sc)
    __shared__ float Gm[L * R + PAD];   // mirror-square gamma (slots init to sc)

    const int b = blockIdx.x;
    const int mbase = b * L * L;
    const int mode = mask_mode(maskspan);

    int pred = (tid < L) && mask_at(maskspan, mode, mbase + tid);
    const int n = __syncthreads_count(pred);

    const float* lg = logits + (size_t)b * L * L * 2;

    // ---- init: sc into both mirror halves ----
    for (int e = tid; e < L * L; e += NT) {
        int i = e >> 7, j = e & (L - 1);
        if (i <= j && j < n) {
            const float* p = lg + (size_t)e * 2;
            float v = lse2(p[0], p[1]);
            Am[i * R + j] = v; Am[j * R + i] = v;
            Gm[i * R + j] = v; Gm[j * R + i] = v;
        }
    }
    __syncthreads();

    // ---- inside: widths 1..n-1 (R4 structure, chunk-batched loads) ----
    // alpha[i,j] = sc + LSE_t( A[i,i+t] + A[i+1+t,j] ), t in [0,w)
    for (int w = 1; w < n; ++w) {
        int c = n - w;
        if (c > 64) {                       // T=8, w <= 63 -> KMAX 8
            int cell = tid >> 3, sub = tid & 7;
            if (cell < c) {
                int i = cell, j = i + w;
                float v[8]; float mloc = -FLT_MAX;
                int KL = load_disp<8, 8>(v, sub, w, w, &Am[i * R + i], &Am[j * R + i + 1], mloc);
                float M = bfly_max<8>(mloc);
                float s = 0.0f; exp_sum<8>(v, KL, M, s);
                float S = bfly_add<8>(s);
                if (sub == 0) {
                    float val = Am[i * R + j] + M + __logf(S);   // slot holds sc
                    Am[i * R + j] = val; Am[j * R + i] = val;
                }
            }
        } else {                            // T=16, w <= 127 -> KMAX 8
            int cell = tid >> 4, sub = tid & 15;
            if (cell < c) {
                int i = cell, j = i + w;
                float v[8]; float mloc = -FLT_MAX;
                int KL = load_disp<16, 8>(v, sub, w, w, &Am[i * R + i], &Am[j * R + i + 1], mloc);
                float M = bfly_max<16>(mloc);
                float s = 0.0f; exp_sum<8>(v, KL, M, s);
                float S = bfly_add<16>(s);
                if (sub == 0) {
                    float val = Am[i * R + j] + M + __logf(S);
                    Am[i * R + j] = val; Am[j * R + i] = val;
                }
            }
        }
        __syncthreads();
    }

    const float logZ = Am[n - 1];   // alpha[0, n-1]

    // ---- outside: widths n-2..1 (R4 structure, chunk-batched loads) ----
    // gamma[i,j] = sc + LSE( k>j: G[i,k]+A[j+1,k] ; k<i: G[k,j]+A[k,i-1] )
    for (int w = n - 2; w >= 1; --w) {
        int c = n - w;
        if (c > 64) {                       // T=8, streams <= 126 -> KMAX 16
            int cell = tid >> 3, sub = tid & 7;
            int i0 = (tid >> 6) << 3;       // wave's first cell (uniform)
            if (cell < c) {
                int i = cell, j = i + w;
                int nt1 = n - 1 - j;
                int im1 = (i >= 1) ? i - 1 : 0;
                int nAmax = n - 1 - i0 - w;          // uniform bound, stream 1
                int nBmax = i0 + 7;                  // uniform bound, stream 2
                float v1[16], v2[16]; float mloc = -FLT_MAX;
                int K1 = load_disp<8, 16>(v1, sub, nt1, nAmax,
                                          &Gm[i * R + j + 1], &Am[(j + 1) * R + j + 1], mloc);
                int K2 = load_disp<8, 16>(v2, sub, i, nBmax,
                                          &Gm[j * R], &Am[im1 * R], mloc);
                float M = bfly_max<8>(mloc);
                float s = 0.0f;
                exp_sum<16>(v1, K1, M, s);
                exp_sum<16>(v2, K2, M, s);
                float S = bfly_add<8>(s);
                if (sub == 0) {
                    float val = Gm[i * R + j] + M + __logf(S);   // slot holds sc
                    Gm[i * R + j] = val; Gm[j * R + i] = val;
                }
            }
        } else {                            // T=16, streams <= 63 -> KMAX 4
            int cell = tid >> 4, sub = tid & 15;
            int i0 = (tid >> 6) << 2;
            if (cell < c) {
                int i = cell, j = i + w;
                int nt1 = n - 1 - j;
                int im1 = (i >= 1) ? i - 1 : 0;
                int nAmax = n - 1 - i0 - w;
                int nBmax = i0 + 3;
                float v1[4], v2[4]; float mloc = -FLT_MAX;
                int K1 = load_disp<16, 4>(v1, sub, nt1, nAmax,
                                          &Gm[i * R + j + 1], &Am[(j + 1) * R + j + 1], mloc);
                int K2 = load_disp<16, 4>(v2, sub, i, nBmax,
                                          &Gm[j * R], &Am[im1 * R], mloc);
                float M = bfly_max<16>(mloc);
                float s = 0.0f;
                exp_sum<4>(v1, K1, M, s);
                exp_sum<4>(v2, K2, M, s);
                float S = bfly_add<16>(s);
                if (sub == 0) {
                    float val = Gm[i * R + j] + M + __logf(S);
                    Gm[i * R + j] = val; Gm[j * R + i] = val;
                }
            }
        }
        __syncthreads();
    }

    // ============ loss phase ============
    const int* si = spans_ind + mbase;
    double local = 0.0;
    {
        int cell = tid >> 3, sub = tid & 7;       // T=8, streams <= 127 -> KMAX 16
        int i0 = (tid >> 6) << 3;
        if (cell < n) {
            int i = cell;
            int nt1 = n - 1 - i;
            int im1 = (i >= 1) ? i - 1 : 0;
            int nAmax = n - 1 - i0;
            int nBmax = i0 + 7;
            float v1[16], v2[16]; float mloc = -FLT_MAX;
            int K1 = load_disp<8, 16>(v1, sub, nt1, nAmax,
                                      &Gm[i * R + i + 1], &Am[(i + 1) * R + i + 1], mloc);
            int K2 = load_disp<8, 16>(v2, sub, i, nBmax,
                                      &Gm[i * R], &Am[im1 * R], mloc);
            float M = bfly_max<8>(mloc);
            float s = 0.0f;
            exp_sum<16>(v1, K1, M, s);
            exp_sum<16>(v2, K2, M, s);
            float S = bfly_add<8>(s);
            if (sub == 0) {
                float beta_ii = M + __logf(S);
                const float* p = lg + ((size_t)i * L + i) * 2;
                int ind = si[i * L + i];
                float lc = (ind == 2) ? p[1] : p[0];
                float logm = beta_ii - logZ + lc;     // alpha_ii == sc_ii cancels
                local += (double)fmaxf(logm, LOGMIN);
            }
        }
    }
    for (int e = tid; e < L * L; e += NT) {
        int i = e >> 7, j = e & (L - 1);
        if (i < j && j < n) {
            const float* p = lg + (size_t)e * 2;
            float a = p[0], cc = p[1];
            float sc = lse2(a, cc);
            int ind = si[e];
            float lc = (ind == 2) ? cc : a;
            float logm = Am[i * R + j] + Gm[i * R + j] - logZ + lc - 2.0f * sc;
            local += (double)fmaxf(logm, LOGMIN);
        }
    }
    for (int off = 32; off > 0; off >>= 1)
        local += __shfl_down(local, off);
    if ((tid & 63) == 0) atomicAdd(&ws[0], local);
    if (tid == 0) atomicAdd(&ws[1], (double)n);
}

// ================= finalize =================
__global__ void finalize_kernel(const double* __restrict__ ws, float* __restrict__ out) {
    double loss_spans = -ws[0] / ws[1];
    double bce = (ws[2] + ws[3]) / ws[4];
    out[0] = (float)(0.5 * loss_spans + 0.5 * bce);
}

extern "C" void kernel_launch(void* const* d_in, const int* in_sizes, int n_in,
                              void* d_out, int out_size, void* d_ws, size_t ws_size,
                              hipStream_t stream) {
    (void)in_sizes; (void)n_in; (void)out_size; (void)ws_size;
    const float* span_logits = (const float*)d_in[0];
    const float* ph          = (const float*)d_in[1];
    const float* pt          = (const float*)d_in[2];
    /* d_in[3] = ph_arc: unused by reference */
    const int*   spans_ind   = (const int*)d_in[4];
    const int*   ph_ind      = (const int*)d_in[5];
    const int*   pt_ind      = (const int*)d_in[6];
    const void*  maskspan    = d_in[7];
    const void*  maskarc     = d_in[8];
    double* ws = (double*)d_ws;
    float* out = (float*)d_out;

    hipMemsetAsync(d_ws, 0, 5 * sizeof(double), stream);
    hipLaunchKernelGGL(tree_dp_kernel, dim3(NB + NBCE), dim3(NT), 0, stream,
                       span_logits, spans_ind, maskspan,
                       ph, pt, ph_ind, pt_ind, maskarc, ws);
    hipLaunchKernelGGL(finalize_kernel, dim3(1), dim3(1), 0, stream, ws, out);
}

// Round 9
// 349.941 us; speedup vs baseline: 1.7771x; 1.4543x over previous
//
#include <hip/hip_runtime.h>
#include <hip/hip_bf16.h>
#include <float.h>

#define NB 32
#define NBCE 32
#define L 128
#define NT 1024
#define R 133                      /* row stride of mirror-square; 133 % 32 == 5 */
#define PAD 256                    /* tail pad: group overreads stay in-array */
#define LOGMIN -87.49823f          /* ln(1e-38) */

// ---- mask dtype runtime detection (element [0] is guaranteed true: lens >= 64) ----
__device__ __forceinline__ int mask_mode(const void* p) {
    unsigned int v = ((const unsigned int*)p)[0];
    if (v == 1u) return 1;
    if (v == 0x3F800000u) return 2;
    return 0;
}
__device__ __forceinline__ bool mask_at(const void* p, int mode, int idx) {
    if (mode == 1) return ((const int*)p)[idx] != 0;
    if (mode == 2) return ((const float*)p)[idx] != 0.0f;
    return ((const unsigned char*)p)[idx] != 0;
}

__device__ __forceinline__ float lse2(float a, float b) {
    return fmaxf(a, b) + log1pf(__expf(-fabsf(a - b)));
}

// ---- DPP butterflies over aligned subgroups of 8 or 16 lanes (R4-proven) ----
template<int C>
__device__ __forceinline__ float dppf(float x) {
    return __int_as_float(__builtin_amdgcn_mov_dpp(__float_as_int(x), C, 0xF, 0xF, true));
}
template<int T>
__device__ __forceinline__ float bfly_max(float x) {
    x = fmaxf(x, dppf<0xB1>(x));
    x = fmaxf(x, dppf<0x4E>(x));
    x = fmaxf(x, dppf<0x141>(x));
    if (T == 16) x = fmaxf(x, dppf<0x140>(x));
    return x;
}
template<int T>
__device__ __forceinline__ float bfly_add(float x) {
    x += dppf<0xB1>(x);
    x += dppf<0x4E>(x);
    x += dppf<0x141>(x);
    if (T == 16) x += dppf<0x140>(x);
    return x;
}

// ---- R4's single-path loop shape, widened to groups of G=min(NUMAX,8) slots.
// All 2G ds_reads of a group are issued before any combine -> 1 waitcnt per group.
// Uniform (subgroup-level) break between groups only. SROA-safe: one code path.
template<int T, int NUMAX>
__device__ __forceinline__ void load_terms8(float* v, int sub, int nterm,
                                            const float* p1, const float* p2, float& mloc) {
    p1 += sub; p2 += sub;
    constexpr int G = (NUMAX < 8) ? NUMAX : 8;
#pragma unroll
    for (int kk = 0; kk < NUMAX; kk += G) {
        if (kk * T >= nterm) break;
        float a[G], b[G];
#pragma unroll
        for (int g = 0; g < G; ++g) a[g] = p1[(kk + g) * T];
#pragma unroll
        for (int g = 0; g < G; ++g) b[g] = p2[(kk + g) * T];
#pragma unroll
        for (int g = 0; g < G; ++g) {
            float val = (sub + (kk + g) * T < nterm) ? (a[g] + b[g]) : -FLT_MAX;
            v[kk + g] = val; mloc = fmaxf(mloc, val);
        }
    }
}
template<int T, int NUMAX>
__device__ __forceinline__ void sum_exp(const float* v, int nterm, float M, float& s) {
#pragma unroll
    for (int kk = 0; kk < NUMAX; kk += 2) {
        if (kk * T >= nterm) break;
        s += __expf(v[kk] - M) + __expf(v[kk + 1] - M);
    }
}

// ================= fused kernel: blocks [0,NB) = per-batch DP; [NB,NB+NBCE) = BCE =================
__global__ __launch_bounds__(NT, 1) void tree_dp_kernel(
    const float* __restrict__ logits,
    const int*   __restrict__ spans_ind,
    const void*  __restrict__ maskspan,
    const float* __restrict__ ph, const float* __restrict__ pt,
    const int* __restrict__ ph_ind, const int* __restrict__ pt_ind,
    const void* __restrict__ maskarc,
    double*      __restrict__ ws)
{
    const int tid = threadIdx.x;

    // ---------------- BCE blocks ----------------
    if (blockIdx.x >= NB) {
        const int mode = mask_mode(maskarc);
        const int tot = NB * L * L;
        double sph = 0.0, spt = 0.0, cnt = 0.0;
        for (int idx = (blockIdx.x - NB) * NT + tid; idx < tot; idx += NBCE * NT) {
            if (mask_at(maskarc, mode, idx)) {
                float x = ph[idx]; float y = (float)ph_ind[idx];
                sph += (double)(fmaxf(x, 0.0f) - x * y + log1pf(__expf(-fabsf(x))));
                x = pt[idx]; y = (float)pt_ind[idx];
                spt += (double)(fmaxf(x, 0.0f) - x * y + log1pf(__expf(-fabsf(x))));
                cnt += 1.0;
            }
        }
        for (int off = 32; off > 0; off >>= 1) {
            sph += __shfl_down(sph, off);
            spt += __shfl_down(spt, off);
            cnt += __shfl_down(cnt, off);
        }
        if ((tid & 63) == 0) {
            atomicAdd(&ws[2], sph); atomicAdd(&ws[3], spt); atomicAdd(&ws[4], cnt);
        }
        return;
    }

    // ---------------- DP blocks ----------------
    __shared__ float Am[L * R + PAD];   // mirror-square alpha (slots init to sc)
    __shared__ float Gm[L * R + PAD];   // mirror-square gamma (slots init to sc)

    const int b = blockIdx.x;
    const int mbase = b * L * L;
    const int mode = mask_mode(maskspan);

    int pred = (tid < L) && mask_at(maskspan, mode, mbase + tid);
    const int n = __syncthreads_count(pred);

    const float* lg = logits + (size_t)b * L * L * 2;

    // ---- init: sc into both mirror halves ----
    for (int e = tid; e < L * L; e += NT) {
        int i = e >> 7, j = e & (L - 1);
        if (i <= j && j < n) {
            const float* p = lg + (size_t)e * 2;
            float v = lse2(p[0], p[1]);
            Am[i * R + j] = v; Am[j * R + i] = v;
            Gm[i * R + j] = v; Gm[j * R + i] = v;
        }
    }
    __syncthreads();

    // ---- inside: widths 1..n-1 (R4 structure, group-8 batched loads) ----
    // alpha[i,j] = sc + LSE_t( A[i,i+t] + A[i+1+t,j] ), t in [0,w)
    for (int w = 1; w < n; ++w) {
        int c = n - w;
        if (c > 64) {                       // T=8, w <= 63 -> NUMAX 8
            int cell = tid >> 3, sub = tid & 7;
            if (cell < c) {
                int i = cell, j = i + w;
                float v[8]; float mloc = -FLT_MAX;
                load_terms8<8, 8>(v, sub, w, &Am[i * R + i], &Am[j * R + i + 1], mloc);
                float M = bfly_max<8>(mloc);
                float s = 0.0f; sum_exp<8, 8>(v, w, M, s);
                float S = bfly_add<8>(s);
                if (sub == 0) {
                    float val = Am[i * R + j] + M + __logf(S);   // slot holds sc
                    Am[i * R + j] = val; Am[j * R + i] = val;
                }
            }
        } else {                            // T=16, w <= 127 -> NUMAX 8
            int cell = tid >> 4, sub = tid & 15;
            if (cell < c) {
                int i = cell, j = i + w;
                float v[8]; float mloc = -FLT_MAX;
                load_terms8<16, 8>(v, sub, w, &Am[i * R + i], &Am[j * R + i + 1], mloc);
                float M = bfly_max<16>(mloc);
                float s = 0.0f; sum_exp<16, 8>(v, w, M, s);
                float S = bfly_add<16>(s);
                if (sub == 0) {
                    float val = Am[i * R + j] + M + __logf(S);
                    Am[i * R + j] = val; Am[j * R + i] = val;
                }
            }
        }
        __syncthreads();
    }

    const float logZ = Am[n - 1];   // alpha[0, n-1]

    // ---- outside: widths n-2..1 (R4 structure, group-8 batched loads) ----
    // gamma[i,j] = sc + LSE( k>j: G[i,k]+A[j+1,k] ; k<i: G[k,j]+A[k,i-1] )
    for (int w = n - 2; w >= 1; --w) {
        int c = n - w;
        if (c > 64) {                       // T=8, streams <= 126 -> NUMAX 16
            int cell = tid >> 3, sub = tid & 7;
            if (cell < c) {
                int i = cell, j = i + w;
                int nt1 = n - 1 - j;
                int im1 = (i >= 1) ? i - 1 : 0;
                float v1[16], v2[16]; float mloc = -FLT_MAX;
                load_terms8<8, 16>(v1, sub, nt1,
                                   &Gm[i * R + j + 1], &Am[(j + 1) * R + j + 1], mloc);
                load_terms8<8, 16>(v2, sub, i,
                                   &Gm[j * R], &Am[im1 * R], mloc);
                float M = bfly_max<8>(mloc);
                float s = 0.0f;
                sum_exp<8, 16>(v1, nt1, M, s);
                sum_exp<8, 16>(v2, i,   M, s);
                float S = bfly_add<8>(s);
                if (sub == 0) {
                    float val = Gm[i * R + j] + M + __logf(S);   // slot holds sc
                    Gm[i * R + j] = val; Gm[j * R + i] = val;
                }
            }
        } else {                            // T=16, streams <= 63 -> NUMAX 4
            int cell = tid >> 4, sub = tid & 15;
            if (cell < c) {
                int i = cell, j = i + w;
                int nt1 = n - 1 - j;
                int im1 = (i >= 1) ? i - 1 : 0;
                float v1[4], v2[4]; float mloc = -FLT_MAX;
                load_terms8<16, 4>(v1, sub, nt1,
                                   &Gm[i * R + j + 1], &Am[(j + 1) * R + j + 1], mloc);
                load_terms8<16, 4>(v2, sub, i,
                                   &Gm[j * R], &Am[im1 * R], mloc);
                float M = bfly_max<16>(mloc);
                float s = 0.0f;
                sum_exp<16, 4>(v1, nt1, M, s);
                sum_exp<16, 4>(v2, i,   M, s);
                float S = bfly_add<16>(s);
                if (sub == 0) {
                    float val = Gm[i * R + j] + M + __logf(S);
                    Gm[i * R + j] = val; Gm[j * R + i] = val;
                }
            }
        }
        __syncthreads();
    }

    // ============ loss phase ============
    const int* si = spans_ind + mbase;
    double local = 0.0;
    {
        int cell = tid >> 3, sub = tid & 7;       // T=8, streams <= 127 -> NUMAX 16
        if (cell < n) {
            int i = cell;
            int nt1 = n - 1 - i;
            int im1 = (i >= 1) ? i - 1 : 0;
            float v1[16], v2[16]; float mloc = -FLT_MAX;
            load_terms8<8, 16>(v1, sub, nt1,
                               &Gm[i * R + i + 1], &Am[(i + 1) * R + i + 1], mloc);
            load_terms8<8, 16>(v2, sub, i,
                               &Gm[i * R], &Am[im1 * R], mloc);
            float M = bfly_max<8>(mloc);
            float s = 0.0f;
            sum_exp<8, 16>(v1, nt1, M, s);
            sum_exp<8, 16>(v2, i,   M, s);
            float S = bfly_add<8>(s);
            if (sub == 0) {
                float beta_ii = M + __logf(S);
                const float* p = lg + ((size_t)i * L + i) * 2;
                int ind = si[i * L + i];
                float lc = (ind == 2) ? p[1] : p[0];
                float logm = beta_ii - logZ + lc;     // alpha_ii == sc_ii cancels
                local += (double)fmaxf(logm, LOGMIN);
            }
        }
    }
    for (int e = tid; e < L * L; e += NT) {
        int i = e >> 7, j = e & (L - 1);
        if (i < j && j < n) {
            const float* p = lg + (size_t)e * 2;
            float a = p[0], cc = p[1];
            float sc = lse2(a, cc);
            int ind = si[e];
            float lc = (ind == 2) ? cc : a;
            float logm = Am[i * R + j] + Gm[i * R + j] - logZ + lc - 2.0f * sc;
            local += (double)fmaxf(logm, LOGMIN);
        }
    }
    for (int off = 32; off > 0; off >>= 1)
        local += __shfl_down(local, off);
    if ((tid & 63) == 0) atomicAdd(&ws[0], local);
    if (tid == 0) atomicAdd(&ws[1], (double)n);
}

// ================= finalize =================
__global__ void finalize_kernel(const double* __restrict__ ws, float* __restrict__ out) {
    double loss_spans = -ws[0] / ws[1];
    double bce = (ws[2] + ws[3]) / ws[4];
    out[0] = (float)(0.5 * loss_spans + 0.5 * bce);
}

extern "C" void kernel_launch(void* const* d_in, const int* in_sizes, int n_in,
                              void* d_out, int out_size, void* d_ws, size_t ws_size,
                              hipStream_t stream) {
    (void)in_sizes; (void)n_in; (void)out_size; (void)ws_size;
    const float* span_logits = (const float*)d_in[0];
    const float* ph          = (const float*)d_in[1];
    const float* pt          = (const float*)d_in[2];
    /* d_in[3] = ph_arc: unused by reference */
    const int*   spans_ind   = (const int*)d_in[4];
    const int*   ph_ind      = (const int*)d_in[5];
    const int*   pt_ind      = (const int*)d_in[6];
    const void*  maskspan    = d_in[7];
    const void*  maskarc     = d_in[8];
    double* ws = (double*)d_ws;
    float* out = (float*)d_out;

    hipMemsetAsync(d_ws, 0, 5 * sizeof(double), stream);
    hipLaunchKernelGGL(tree_dp_kernel, dim3(NB + NBCE), dim3(NT), 0, stream,
                       span_logits, spans_ind, maskspan,
                       ph, pt, ph_ind, pt_ind, maskarc, ws);
    hipLaunchKernelGGL(finalize_kernel, dim3(1), dim3(1), 0, stream, ws, out);
}